// Round 1
// baseline (480.536 us; speedup 1.0000x reference)
//
#include <hip/hip_runtime.h>
#include <stdint.h>

#pragma clang fp contract(off)

#define BB 32
#define NN 200000
#define KK 500
#define KEEPN 100
#define CAND_CAP 4096
#define CONF 0.05f
#define NMSTHR 0.5f

// ---- workspace layout (bytes) ----
// 0      : hist1  32*256*4 = 32768
// 32768  : hist2  32768
// 65536  : cnt    128
// 65664  : b1arr  128
// 65792  : cnthi  128
// 65920  : p16    128
// 66048  : cand   32*4096*8 = 1048576
// total 1114624

__device__ __forceinline__ unsigned int ordkey(float s) {
    unsigned int u = __float_as_uint(s);
    return (u & 0x80000000u) ? ~u : (u | 0x80000000u);
}

// ---- level-1 histogram: bin = ordered >> 24 ----
__global__ __launch_bounds__(256) void hist1_kernel(const float* __restrict__ ps,
                                                    unsigned int* __restrict__ hist1) {
    __shared__ unsigned int lh[4][256];
    const int t = threadIdx.x;
    for (int w = 0; w < 4; ++w) lh[w][t] = 0;
    __syncthreads();
    const int wv = t >> 6;
    const int b = blockIdx.y;
    const float* p = ps + (size_t)b * NN;
    const int base = blockIdx.x * 2048;
    for (int k = 0; k < 8; ++k) {
        int n = base + k * 256 + t;
        if (n < NN) atomicAdd(&lh[wv][ordkey(p[n]) >> 24], 1u);
    }
    __syncthreads();
    unsigned int s = lh[0][t] + lh[1][t] + lh[2][t] + lh[3][t];
    if (s) atomicAdd(&hist1[b * 256 + t], s);
}

// ---- scan level-1: suffix sums, find bin b1 where cumulative-from-top crosses KK ----
__global__ __launch_bounds__(256) void scan1_kernel(const unsigned int* __restrict__ hist1,
                                                    unsigned int* __restrict__ b1arr,
                                                    unsigned int* __restrict__ cnthi) {
    __shared__ unsigned int sh[256];
    const int t = threadIdx.x, b = blockIdx.x;
    sh[t] = hist1[b * 256 + t];
    __syncthreads();
    for (int d = 1; d < 256; d <<= 1) {
        unsigned int add = (t + d < 256) ? sh[t + d] : 0u;
        __syncthreads();
        sh[t] += add;
        __syncthreads();
    }
    unsigned int st = sh[t];
    unsigned int stn = (t < 255) ? sh[t + 1] : 0u;
    if (st >= (unsigned)KK && stn < (unsigned)KK) { b1arr[b] = (unsigned)t; cnthi[b] = stn; }
}

// ---- level-2 histogram within bin b1: bin = (ordered >> 16) & 0xFF ----
__global__ __launch_bounds__(256) void hist2_kernel(const float* __restrict__ ps,
                                                    const unsigned int* __restrict__ b1arr,
                                                    unsigned int* __restrict__ hist2) {
    __shared__ unsigned int lh[4][256];
    const int t = threadIdx.x;
    for (int w = 0; w < 4; ++w) lh[w][t] = 0;
    __syncthreads();
    const int wv = t >> 6;
    const int b = blockIdx.y;
    const unsigned int b1 = b1arr[b];
    const float* p = ps + (size_t)b * NN;
    const int base = blockIdx.x * 2048;
    for (int k = 0; k < 8; ++k) {
        int n = base + k * 256 + t;
        if (n < NN) {
            unsigned int u = ordkey(p[n]);
            if ((u >> 24) == b1) atomicAdd(&lh[wv][(u >> 16) & 0xFFu], 1u);
        }
    }
    __syncthreads();
    unsigned int s = lh[0][t] + lh[1][t] + lh[2][t] + lh[3][t];
    if (s) atomicAdd(&hist2[b * 256 + t], s);
}

// ---- scan level-2: final 16-bit prefix ----
__global__ __launch_bounds__(256) void scan2_kernel(const unsigned int* __restrict__ hist2,
                                                    const unsigned int* __restrict__ b1arr,
                                                    const unsigned int* __restrict__ cnthi,
                                                    unsigned int* __restrict__ p16arr) {
    __shared__ unsigned int sh[256];
    const int t = threadIdx.x, b = blockIdx.x;
    sh[t] = hist2[b * 256 + t];
    __syncthreads();
    for (int d = 1; d < 256; d <<= 1) {
        unsigned int add = (t + d < 256) ? sh[t + d] : 0u;
        __syncthreads();
        sh[t] += add;
        __syncthreads();
    }
    unsigned int c0 = cnthi[b];
    unsigned int st = c0 + sh[t];
    unsigned int stn = c0 + ((t < 255) ? sh[t + 1] : 0u);
    if (st >= (unsigned)KK && stn < (unsigned)KK)
        p16arr[b] = (b1arr[b] << 8) | (unsigned)t;
}

// ---- compact candidates with (ordered>>16) >= prefix as 64-bit keys ----
__global__ __launch_bounds__(256) void compact_kernel(const float* __restrict__ ps,
                                                      const unsigned int* __restrict__ p16arr,
                                                      unsigned long long* __restrict__ cand,
                                                      unsigned int* __restrict__ cnt) {
    const int b = blockIdx.y;
    const unsigned int p16 = p16arr[b];
    const float* p = ps + (size_t)b * NN;
    const int base = blockIdx.x * 2048 + threadIdx.x;
    for (int k = 0; k < 8; ++k) {
        int n = base + k * 256;
        if (n < NN) {
            unsigned int u = ordkey(p[n]);
            if ((u >> 16) >= p16) {
                unsigned int pos = atomicAdd(&cnt[b], 1u);
                if (pos < CAND_CAP)
                    cand[(size_t)b * CAND_CAP + pos] =
                        ((unsigned long long)u << 32) | (unsigned int)(~(unsigned int)n);
            }
        }
    }
}

// ---- per-batch: sort candidates, top-500, NMS, compact outputs ----
__global__ __launch_bounds__(1024) void final_kernel(const float* __restrict__ pboxes,
                                                     const int* __restrict__ plabels,
                                                     const unsigned long long* __restrict__ cand,
                                                     const unsigned int* __restrict__ cnt,
                                                     float* __restrict__ out) {
    __shared__ unsigned long long sbuf[4096];   // bitonic keys, then IoU bitmask rows
    __shared__ float sboxes[KK][4];
    __shared__ float sshift[KK][4];
    __shared__ float sscore[KK];
    __shared__ int slabel[KK];
    __shared__ unsigned long long validw[8];
    __shared__ int kept[KEEPN];
    __shared__ int s_nk;
    __shared__ float red[1024];
    __shared__ float s_maxc;

    const int b = blockIdx.x;
    const int tid = threadIdx.x;

    int m = (int)cnt[b];
    if (m > CAND_CAP) m = CAND_CAP;
    int n2 = 512;
    while (n2 < m) n2 <<= 1;

    for (int i = tid; i < n2; i += 1024)
        sbuf[i] = (i < m) ? cand[(size_t)b * CAND_CAP + i] : 0ULL;
    __syncthreads();

    // bitonic sort descending
    for (int kk = 2; kk <= n2; kk <<= 1) {
        for (int j = kk >> 1; j > 0; j >>= 1) {
            for (int i = tid; i < n2; i += 1024) {
                int p = i ^ j;
                if (p > i) {
                    unsigned long long a = sbuf[i], c = sbuf[p];
                    bool up = ((i & kk) == 0);
                    if (up ? (a < c) : (a > c)) { sbuf[i] = c; sbuf[p] = a; }
                }
            }
            __syncthreads();
        }
    }

    // extract top-500: index, exact score, gather boxes/labels
    if (tid < KK) {
        unsigned long long key = sbuf[tid];
        unsigned int lo = (unsigned int)key;
        unsigned int hi = (unsigned int)(key >> 32);
        int idx = (key == 0ULL) ? 0 : (int)(~lo);
        unsigned int bits = (hi & 0x80000000u) ? (hi & 0x7FFFFFFFu) : ~hi;
        float sc = (key == 0ULL) ? -1.0f : __uint_as_float(bits);
        sscore[tid] = sc;
        const float4 bx = *(const float4*)(pboxes + (((size_t)b * NN + (size_t)idx) << 2));
        sboxes[tid][0] = bx.x; sboxes[tid][1] = bx.y;
        sboxes[tid][2] = bx.z; sboxes[tid][3] = bx.w;
        slabel[tid] = plabels[(size_t)b * NN + idx];
    }
    __syncthreads();

    // valid mask bits (wave ballots)
    bool v = (tid < KK) && (sscore[tid] > CONF);
    unsigned long long bm = __ballot(v);
    if ((tid & 63) == 0) {
        int w = tid >> 6;
        if (w < 8) validw[w] = bm;
    }

    // max_coord over valid boxes (masked with 0, all coords >= 0)
    float lm = 0.0f;
    if (v) lm = fmaxf(fmaxf(sboxes[tid][0], sboxes[tid][1]),
                      fmaxf(sboxes[tid][2], sboxes[tid][3]));
    red[tid] = lm;
    __syncthreads();
    for (int s = 512; s > 0; s >>= 1) {
        if (tid < s) red[tid] = fmaxf(red[tid], red[tid + s]);
        __syncthreads();
    }
    if (tid == 0) s_maxc = red[0];
    __syncthreads();

    // label-offset shifted boxes (exact reference arithmetic: off rounded first, then added)
    if (tid < KK) {
        float off = (float)slabel[tid] * (s_maxc + 1.0f);
        sshift[tid][0] = sboxes[tid][0] + off;
        sshift[tid][1] = sboxes[tid][1] + off;
        sshift[tid][2] = sboxes[tid][2] + off;
        sshift[tid][3] = sboxes[tid][3] + off;
    }
    __syncthreads();

    // IoU > thr bitmask: row i, word w covers columns w*64..w*64+63 (full symmetric rows)
    for (int task = tid; task < KK * 8; task += 1024) {
        int i = task >> 3, w = task & 7;
        float a0 = sshift[i][0], a1 = sshift[i][1], a2 = sshift[i][2], a3 = sshift[i][3];
        float areaA = (a2 - a0) * (a3 - a1);
        unsigned long long word = 0ULL;
        int jbase = w << 6;
        int jn = KK - jbase; if (jn > 64) jn = 64;
        for (int t2 = 0; t2 < jn; ++t2) {
            int j = jbase + t2;
            float b0 = sshift[j][0], b1f = sshift[j][1], b2f = sshift[j][2], b3f = sshift[j][3];
            float lt0 = fmaxf(a0, b0), lt1 = fmaxf(a1, b1f);
            float rb0 = fminf(a2, b2f), rb1 = fminf(a3, b3f);
            float ww = fmaxf(rb0 - lt0, 0.0f), hh = fmaxf(rb1 - lt1, 0.0f);
            float inter = ww * hh;
            float areaB = (b2f - b0) * (b3f - b1f);
            float iou = inter / (areaA + areaB - inter);
            if (iou > NMSTHR) word |= (1ULL << t2);
        }
        sbuf[task] = word;
    }
    __syncthreads();

    // greedy scan on wave 0; early-exit at KEEPN kept (later kept can't affect first 100)
    if (tid < 64) {
        const int lane = tid;
        unsigned long long remv = 0ULL;
        unsigned long long vw_reg = (lane < 8) ? validw[lane] : 0ULL;
        int nk = 0;
        for (int i = 0; i < KK && nk < KEEPN; ++i) {
            int w = i >> 6, bpos = i & 63;
            unsigned long long rw = __shfl(remv, w);
            unsigned long long vv = __shfl(vw_reg, w);
            bool alive = (((vv >> bpos) & 1ULL) != 0ULL) && (((rw >> bpos) & 1ULL) == 0ULL);
            if (alive) {
                if (lane == 0) kept[nk] = i;
                unsigned long long roww = (lane < 8) ? sbuf[i * 8 + lane] : 0ULL;
                remv |= roww;
                nk++;
            }
        }
        if (lane == 0) s_nk = nk;
    }
    __syncthreads();

    // outputs, all as float32, concatenated in reference return order
    if (tid < KEEPN) {
        const int O_BOX = BB * KEEPN;          // 3200
        const int O_LAB = BB * KEEPN * 5;      // 16000
        const int O_SCO = BB * KEEPN * 6;      // 19200
        const int O_VAL = BB * KEEPN * 7;      // 22400
        bool q = tid < s_nk;
        int i = q ? kept[tid] : 0;
        int g = b * KEEPN + tid;
        out[g]             = q ? (float)b : -1.0f;
        out[O_BOX + g * 4 + 0] = q ? sboxes[i][0] : 0.0f;
        out[O_BOX + g * 4 + 1] = q ? sboxes[i][1] : 0.0f;
        out[O_BOX + g * 4 + 2] = q ? sboxes[i][2] : 0.0f;
        out[O_BOX + g * 4 + 3] = q ? sboxes[i][3] : 0.0f;
        out[O_LAB + g]     = q ? (float)slabel[i] : -1.0f;
        out[O_SCO + g]     = q ? sscore[i] : 0.0f;
        out[O_VAL + g]     = q ? 1.0f : 0.0f;
    }
}

extern "C" void kernel_launch(void* const* d_in, const int* in_sizes, int n_in,
                              void* d_out, int out_size, void* d_ws, size_t ws_size,
                              hipStream_t stream) {
    const float* pscores = (const float*)d_in[0];
    const float* pboxes  = (const float*)d_in[1];
    const int*   plabels = (const int*)d_in[2];
    float* out = (float*)d_out;

    uint8_t* ws = (uint8_t*)d_ws;
    unsigned int* hist1 = (unsigned int*)(ws + 0);
    unsigned int* hist2 = (unsigned int*)(ws + 32768);
    unsigned int* cnt   = (unsigned int*)(ws + 65536);
    unsigned int* b1arr = (unsigned int*)(ws + 65664);
    unsigned int* cnthi = (unsigned int*)(ws + 65792);
    unsigned int* p16   = (unsigned int*)(ws + 65920);
    unsigned long long* cand = (unsigned long long*)(ws + 66048);

    // zero hist1+hist2+cnt (ws is re-poisoned to 0xAA before every launch)
    hipMemsetAsync(ws, 0, 65664, stream);

    const dim3 gscan((NN + 2047) / 2048, BB);  // 98 x 32
    hist1_kernel<<<gscan, 256, 0, stream>>>(pscores, hist1);
    scan1_kernel<<<BB, 256, 0, stream>>>(hist1, b1arr, cnthi);
    hist2_kernel<<<gscan, 256, 0, stream>>>(pscores, b1arr, hist2);
    scan2_kernel<<<BB, 256, 0, stream>>>(hist2, b1arr, cnthi, p16);
    compact_kernel<<<gscan, 256, 0, stream>>>(pscores, p16, cand, cnt);
    final_kernel<<<BB, 1024, 0, stream>>>(pboxes, plabels, cand, cnt, out);
}

// Round 2
// 271.986 us; speedup vs baseline: 1.7668x; 1.7668x over previous
//
#include <hip/hip_runtime.h>
#include <stdint.h>

#pragma clang fp contract(off)

#define BB 32
#define NN 200000
#define N4 50000
#define KK 500
#define KEEPN 100
#define CAND_CAP 4096
#define CONF 0.05f
#define NMSTHR 0.5f
#define CNT_STRIDE 16   // one counter per 64B to kill cache-line ping-pong

// ---- workspace layout (bytes) ----
// 0      : hist1  32*256*4 = 32768
// 32768  : hist2  32768
// 65536  : cnt    32*64 = 2048 (padded, one per 64B)
// 67584  : b1arr  128
// 67712  : cnthi  128
// 67840  : p16    128
// 67968  : cand   32*4096*8 = 1048576

__device__ __forceinline__ unsigned int ordkey(float s) {
    unsigned int u = __float_as_uint(s);
    return (u & 0x80000000u) ? ~u : (u | 0x80000000u);
}

// ---- level-1 histogram: bin = ordered >> 24, 8 sub-hists by lane&7 ----
__global__ __launch_bounds__(256) void hist1_kernel(const float4* __restrict__ ps4,
                                                    unsigned int* __restrict__ hist1) {
    __shared__ unsigned int lh[256][8];
    const int t = threadIdx.x;
    for (int i = t; i < 256 * 8; i += 256) ((unsigned int*)lh)[i] = 0;
    __syncthreads();
    const int b = blockIdx.y;
    const int sub = t & 7;
    const float4* p = ps4 + (size_t)b * N4;
    for (int i = blockIdx.x * 256 + t; i < N4; i += 16 * 256) {
        float4 v = p[i];
        atomicAdd(&lh[ordkey(v.x) >> 24][sub], 1u);
        atomicAdd(&lh[ordkey(v.y) >> 24][sub], 1u);
        atomicAdd(&lh[ordkey(v.z) >> 24][sub], 1u);
        atomicAdd(&lh[ordkey(v.w) >> 24][sub], 1u);
    }
    __syncthreads();
    unsigned int s = 0;
    for (int w = 0; w < 8; ++w) s += lh[t][w];
    if (s) atomicAdd(&hist1[b * 256 + t], s);
}

// ---- scan level-1: suffix sums, find bin where cumulative-from-top crosses KK ----
__global__ __launch_bounds__(256) void scan1_kernel(const unsigned int* __restrict__ hist1,
                                                    unsigned int* __restrict__ b1arr,
                                                    unsigned int* __restrict__ cnthi) {
    __shared__ unsigned int sh[256];
    const int t = threadIdx.x, b = blockIdx.x;
    sh[t] = hist1[b * 256 + t];
    __syncthreads();
    for (int d = 1; d < 256; d <<= 1) {
        unsigned int add = (t + d < 256) ? sh[t + d] : 0u;
        __syncthreads();
        sh[t] += add;
        __syncthreads();
    }
    unsigned int st = sh[t];
    unsigned int stn = (t < 255) ? sh[t + 1] : 0u;
    if (st >= (unsigned)KK && stn < (unsigned)KK) { b1arr[b] = (unsigned)t; cnthi[b] = stn; }
}

// ---- level-2 histogram within bin b1: bin = (ordered >> 16) & 0xFF ----
__global__ __launch_bounds__(256) void hist2_kernel(const float4* __restrict__ ps4,
                                                    const unsigned int* __restrict__ b1arr,
                                                    unsigned int* __restrict__ hist2) {
    __shared__ unsigned int lh[256][8];
    const int t = threadIdx.x;
    for (int i = t; i < 256 * 8; i += 256) ((unsigned int*)lh)[i] = 0;
    __syncthreads();
    const int b = blockIdx.y;
    const unsigned int b1 = b1arr[b];
    const int sub = t & 7;
    const float4* p = ps4 + (size_t)b * N4;
    for (int i = blockIdx.x * 256 + t; i < N4; i += 16 * 256) {
        float4 v = p[i];
        unsigned int u;
        u = ordkey(v.x); if ((u >> 24) == b1) atomicAdd(&lh[(u >> 16) & 0xFFu][sub], 1u);
        u = ordkey(v.y); if ((u >> 24) == b1) atomicAdd(&lh[(u >> 16) & 0xFFu][sub], 1u);
        u = ordkey(v.z); if ((u >> 24) == b1) atomicAdd(&lh[(u >> 16) & 0xFFu][sub], 1u);
        u = ordkey(v.w); if ((u >> 24) == b1) atomicAdd(&lh[(u >> 16) & 0xFFu][sub], 1u);
    }
    __syncthreads();
    unsigned int s = 0;
    for (int w = 0; w < 8; ++w) s += lh[t][w];
    if (s) atomicAdd(&hist2[b * 256 + t], s);
}

// ---- scan level-2: final 16-bit prefix ----
__global__ __launch_bounds__(256) void scan2_kernel(const unsigned int* __restrict__ hist2,
                                                    const unsigned int* __restrict__ b1arr,
                                                    const unsigned int* __restrict__ cnthi,
                                                    unsigned int* __restrict__ p16arr) {
    __shared__ unsigned int sh[256];
    const int t = threadIdx.x, b = blockIdx.x;
    sh[t] = hist2[b * 256 + t];
    __syncthreads();
    for (int d = 1; d < 256; d <<= 1) {
        unsigned int add = (t + d < 256) ? sh[t + d] : 0u;
        __syncthreads();
        sh[t] += add;
        __syncthreads();
    }
    unsigned int c0 = cnthi[b];
    unsigned int st = c0 + sh[t];
    unsigned int stn = c0 + ((t < 255) ? sh[t + 1] : 0u);
    if (st >= (unsigned)KK && stn < (unsigned)KK)
        p16arr[b] = (b1arr[b] << 8) | (unsigned)t;
}

// ---- compact candidates: LDS staging, ONE global atomic per block ----
__global__ __launch_bounds__(256) void compact_kernel(const float4* __restrict__ ps4,
                                                      const unsigned int* __restrict__ p16arr,
                                                      unsigned long long* __restrict__ cand,
                                                      unsigned int* __restrict__ cnt) {
    __shared__ unsigned long long sl[2048];   // block covers 2048 elems -> can't overflow
    __shared__ int lcnt;
    __shared__ unsigned int lbase;
    const int t = threadIdx.x;
    if (t == 0) lcnt = 0;
    __syncthreads();
    const int b = blockIdx.y;
    const unsigned int p16 = p16arr[b];
    const float4* p = ps4 + (size_t)b * N4;
    for (int k = 0; k < 2; ++k) {
        int i4 = blockIdx.x * 512 + k * 256 + t;
        if (i4 < N4) {
            float4 v = p[i4];
            int n = i4 << 2;
            unsigned int u;
            u = ordkey(v.x);
            if ((u >> 16) >= p16) { int pos = atomicAdd(&lcnt, 1);
                sl[pos] = ((unsigned long long)u << 32) | (unsigned int)(~(unsigned int)(n)); }
            u = ordkey(v.y);
            if ((u >> 16) >= p16) { int pos = atomicAdd(&lcnt, 1);
                sl[pos] = ((unsigned long long)u << 32) | (unsigned int)(~(unsigned int)(n + 1)); }
            u = ordkey(v.z);
            if ((u >> 16) >= p16) { int pos = atomicAdd(&lcnt, 1);
                sl[pos] = ((unsigned long long)u << 32) | (unsigned int)(~(unsigned int)(n + 2)); }
            u = ordkey(v.w);
            if ((u >> 16) >= p16) { int pos = atomicAdd(&lcnt, 1);
                sl[pos] = ((unsigned long long)u << 32) | (unsigned int)(~(unsigned int)(n + 3)); }
        }
    }
    __syncthreads();
    if (t == 0 && lcnt > 0) lbase = atomicAdd(&cnt[b * CNT_STRIDE], (unsigned)lcnt);
    __syncthreads();
    for (int i = t; i < lcnt; i += 256) {
        unsigned int pos = lbase + (unsigned)i;
        if (pos < CAND_CAP) cand[(size_t)b * CAND_CAP + pos] = sl[i];
    }
}

// ---- per-batch: sort candidates, top-500, NMS, compact outputs ----
__global__ __launch_bounds__(1024) void final_kernel(const float* __restrict__ pboxes,
                                                     const int* __restrict__ plabels,
                                                     const unsigned long long* __restrict__ cand,
                                                     const unsigned int* __restrict__ cnt,
                                                     float* __restrict__ out) {
    __shared__ unsigned long long sbuf[4096];   // bitonic keys, then IoU bitmask rows
    __shared__ float sboxes[KK][4];
    __shared__ float sshift[KK][4];
    __shared__ float sscore[KK];
    __shared__ int slabel[KK];
    __shared__ unsigned long long validw[8];
    __shared__ int kept[KEEPN];
    __shared__ int s_nk;
    __shared__ float red[1024];
    __shared__ float s_maxc;

    const int b = blockIdx.x;
    const int tid = threadIdx.x;

    int m = (int)cnt[b * CNT_STRIDE];
    if (m > CAND_CAP) m = CAND_CAP;
    int n2 = 512;
    while (n2 < m) n2 <<= 1;

    for (int i = tid; i < n2; i += 1024)
        sbuf[i] = (i < m) ? cand[(size_t)b * CAND_CAP + i] : 0ULL;
    __syncthreads();

    // bitonic sort descending
    for (int kk = 2; kk <= n2; kk <<= 1) {
        for (int j = kk >> 1; j > 0; j >>= 1) {
            for (int i = tid; i < n2; i += 1024) {
                int p = i ^ j;
                if (p > i) {
                    unsigned long long a = sbuf[i], c = sbuf[p];
                    bool up = ((i & kk) == 0);
                    if (up ? (a < c) : (a > c)) { sbuf[i] = c; sbuf[p] = a; }
                }
            }
            __syncthreads();
        }
    }

    // extract top-500: index, exact score, gather boxes/labels
    if (tid < KK) {
        unsigned long long key = sbuf[tid];
        unsigned int lo = (unsigned int)key;
        unsigned int hi = (unsigned int)(key >> 32);
        int idx = (key == 0ULL) ? 0 : (int)(~lo);
        unsigned int bits = (hi & 0x80000000u) ? (hi & 0x7FFFFFFFu) : ~hi;
        float sc = (key == 0ULL) ? -1.0f : __uint_as_float(bits);
        sscore[tid] = sc;
        const float4 bx = *(const float4*)(pboxes + (((size_t)b * NN + (size_t)idx) << 2));
        sboxes[tid][0] = bx.x; sboxes[tid][1] = bx.y;
        sboxes[tid][2] = bx.z; sboxes[tid][3] = bx.w;
        slabel[tid] = plabels[(size_t)b * NN + idx];
    }
    __syncthreads();

    // valid mask bits (wave ballots)
    bool v = (tid < KK) && (sscore[tid] > CONF);
    unsigned long long bm = __ballot(v);
    if ((tid & 63) == 0) {
        int w = tid >> 6;
        if (w < 8) validw[w] = bm;
    }

    // max_coord over valid boxes (masked with 0, all coords >= 0)
    float lm = 0.0f;
    if (v) lm = fmaxf(fmaxf(sboxes[tid][0], sboxes[tid][1]),
                      fmaxf(sboxes[tid][2], sboxes[tid][3]));
    red[tid] = lm;
    __syncthreads();
    for (int s = 512; s > 0; s >>= 1) {
        if (tid < s) red[tid] = fmaxf(red[tid], red[tid + s]);
        __syncthreads();
    }
    if (tid == 0) s_maxc = red[0];
    __syncthreads();

    // label-offset shifted boxes (exact reference arithmetic)
    if (tid < KK) {
        float off = (float)slabel[tid] * (s_maxc + 1.0f);
        sshift[tid][0] = sboxes[tid][0] + off;
        sshift[tid][1] = sboxes[tid][1] + off;
        sshift[tid][2] = sboxes[tid][2] + off;
        sshift[tid][3] = sboxes[tid][3] + off;
    }
    __syncthreads();

    // IoU > thr bitmask: row i, word w covers columns w*64..w*64+63
    for (int task = tid; task < KK * 8; task += 1024) {
        int i = task >> 3, w = task & 7;
        float a0 = sshift[i][0], a1 = sshift[i][1], a2 = sshift[i][2], a3 = sshift[i][3];
        float areaA = (a2 - a0) * (a3 - a1);
        unsigned long long word = 0ULL;
        int jbase = w << 6;
        int jn = KK - jbase; if (jn > 64) jn = 64;
        for (int t2 = 0; t2 < jn; ++t2) {
            int j = jbase + t2;
            float b0 = sshift[j][0], b1f = sshift[j][1], b2f = sshift[j][2], b3f = sshift[j][3];
            float lt0 = fmaxf(a0, b0), lt1 = fmaxf(a1, b1f);
            float rb0 = fminf(a2, b2f), rb1 = fminf(a3, b3f);
            float ww = fmaxf(rb0 - lt0, 0.0f), hh = fmaxf(rb1 - lt1, 0.0f);
            float inter = ww * hh;
            float areaB = (b2f - b0) * (b3f - b1f);
            float iou = inter / (areaA + areaB - inter);
            if (iou > NMSTHR) word |= (1ULL << t2);
        }
        sbuf[task] = word;
    }
    __syncthreads();

    // greedy scan on wave 0; early-exit at KEEPN kept
    if (tid < 64) {
        const int lane = tid;
        unsigned long long remv = 0ULL;
        unsigned long long vw_reg = (lane < 8) ? validw[lane] : 0ULL;
        int nk = 0;
        for (int i = 0; i < KK && nk < KEEPN; ++i) {
            int w = i >> 6, bpos = i & 63;
            unsigned long long rw = __shfl(remv, w);
            unsigned long long vv = __shfl(vw_reg, w);
            bool alive = (((vv >> bpos) & 1ULL) != 0ULL) && (((rw >> bpos) & 1ULL) == 0ULL);
            if (alive) {
                if (lane == 0) kept[nk] = i;
                unsigned long long roww = (lane < 8) ? sbuf[i * 8 + lane] : 0ULL;
                remv |= roww;
                nk++;
            }
        }
        if (lane == 0) s_nk = nk;
    }
    __syncthreads();

    // outputs, all as float32, concatenated in reference return order
    if (tid < KEEPN) {
        const int O_BOX = BB * KEEPN;          // 3200
        const int O_LAB = BB * KEEPN * 5;      // 16000
        const int O_SCO = BB * KEEPN * 6;      // 19200
        const int O_VAL = BB * KEEPN * 7;      // 22400
        bool q = tid < s_nk;
        int i = q ? kept[tid] : 0;
        int g = b * KEEPN + tid;
        out[g]             = q ? (float)b : -1.0f;
        out[O_BOX + g * 4 + 0] = q ? sboxes[i][0] : 0.0f;
        out[O_BOX + g * 4 + 1] = q ? sboxes[i][1] : 0.0f;
        out[O_BOX + g * 4 + 2] = q ? sboxes[i][2] : 0.0f;
        out[O_BOX + g * 4 + 3] = q ? sboxes[i][3] : 0.0f;
        out[O_LAB + g]     = q ? (float)slabel[i] : -1.0f;
        out[O_SCO + g]     = q ? sscore[i] : 0.0f;
        out[O_VAL + g]     = q ? 1.0f : 0.0f;
    }
}

extern "C" void kernel_launch(void* const* d_in, const int* in_sizes, int n_in,
                              void* d_out, int out_size, void* d_ws, size_t ws_size,
                              hipStream_t stream) {
    const float* pscores = (const float*)d_in[0];
    const float* pboxes  = (const float*)d_in[1];
    const int*   plabels = (const int*)d_in[2];
    float* out = (float*)d_out;

    uint8_t* ws = (uint8_t*)d_ws;
    unsigned int* hist1 = (unsigned int*)(ws + 0);
    unsigned int* hist2 = (unsigned int*)(ws + 32768);
    unsigned int* cnt   = (unsigned int*)(ws + 65536);
    unsigned int* b1arr = (unsigned int*)(ws + 67584);
    unsigned int* cnthi = (unsigned int*)(ws + 67712);
    unsigned int* p16   = (unsigned int*)(ws + 67840);
    unsigned long long* cand = (unsigned long long*)(ws + 67968);

    hipMemsetAsync(ws, 0, 67968, stream);

    const dim3 ghist(16, BB);
    const dim3 gcomp((N4 + 511) / 512, BB);   // 98 x 32
    hist1_kernel<<<ghist, 256, 0, stream>>>((const float4*)pscores, hist1);
    scan1_kernel<<<BB, 256, 0, stream>>>(hist1, b1arr, cnthi);
    hist2_kernel<<<ghist, 256, 0, stream>>>((const float4*)pscores, b1arr, hist2);
    scan2_kernel<<<BB, 256, 0, stream>>>(hist2, b1arr, cnthi, p16);
    compact_kernel<<<gcomp, 256, 0, stream>>>((const float4*)pscores, p16, cand, cnt);
    final_kernel<<<BB, 1024, 0, stream>>>(pboxes, plabels, cand, cnt, out);
}

// Round 3
// 229.613 us; speedup vs baseline: 2.0928x; 1.1845x over previous
//
#include <hip/hip_runtime.h>
#include <stdint.h>

#pragma clang fp contract(off)

#define BB 32
#define NN 200000
#define N4 50000
#define KK 500
#define KEEPN 100
#define CAND_CAP 4096
#define CONF 0.05f
#define NMSTHR 0.5f
#define CNT_STRIDE 16
#define HBINS 16384
#define HSHIFT 18          // ordkey >> 18 = top 14 bits

typedef unsigned long long u64;

// ---- workspace layout (bytes) ----
// 0       : hist   32*16384*4 = 2097152   (memset to 0 each call)
// 2097152 : cnt    32*16*4 = 2048         (zeroed by scan_kernel)
// 2099200 : p14    128
// 2099328 : cand   32*4096*8 = 1048576

__device__ __forceinline__ unsigned int ordkey(float s) {
    unsigned int u = __float_as_uint(s);
    return (u & 0x80000000u) ? ~u : (u | 0x80000000u);
}

// ---- 14-bit histogram: bin = ordered >> 18. Hot bin only ~3% of elems. ----
__global__ __launch_bounds__(512) void hist_kernel(const float4* __restrict__ ps4,
                                                   unsigned int* __restrict__ hist) {
    __shared__ unsigned int lh[HBINS];
    const int t = threadIdx.x;
    for (int i = t; i < HBINS; i += 512) lh[i] = 0;
    __syncthreads();
    const int b = blockIdx.y;
    const float4* p = ps4 + (size_t)b * N4;
    for (int i = blockIdx.x * 512 + t; i < N4; i += 8 * 512) {
        float4 v = p[i];
        atomicAdd(&lh[ordkey(v.x) >> HSHIFT], 1u);
        atomicAdd(&lh[ordkey(v.y) >> HSHIFT], 1u);
        atomicAdd(&lh[ordkey(v.z) >> HSHIFT], 1u);
        atomicAdd(&lh[ordkey(v.w) >> HSHIFT], 1u);
    }
    __syncthreads();
    unsigned int* hb = hist + (size_t)b * HBINS;
    for (int i = t; i < HBINS; i += 512) {
        unsigned int s = lh[i];
        if (s) atomicAdd(&hb[i], s);
    }
}

// ---- per-batch: find 14-bit prefix whose suffix-count crosses KK; zero cnt ----
__global__ __launch_bounds__(1024) void scan_kernel(const unsigned int* __restrict__ hist,
                                                    unsigned int* __restrict__ p14arr,
                                                    unsigned int* __restrict__ cnt) {
    __shared__ unsigned int partial[1024];
    const int t = threadIdx.x, b = blockIdx.x;
    if (t == 0) cnt[b * CNT_STRIDE] = 0;
    const unsigned int* hb = hist + (size_t)b * HBINS;
    unsigned int v[16];
    unsigned int tot = 0;
    for (int j = 0; j < 16; ++j) { v[j] = hb[t * 16 + j]; tot += v[j]; }
    partial[t] = tot;
    __syncthreads();
    for (int d = 1; d < 1024; d <<= 1) {
        unsigned int add = (t + d < 1024) ? partial[t + d] : 0u;
        __syncthreads();
        partial[t] += add;
        __syncthreads();
    }
    unsigned int after = (t < 1023) ? partial[t + 1] : 0u;
    // descending through this thread's 16 bins
    unsigned int sn = after;
    for (int j = 15; j >= 0; --j) {
        unsigned int s = sn + v[j];
        if (s >= (unsigned)KK && sn < (unsigned)KK) p14arr[b] = (unsigned)(t * 16 + j);
        sn = s;
    }
}

// ---- compact candidates (ordered>>18 >= p14): LDS staging, 1 atomic/block ----
__global__ __launch_bounds__(256) void compact_kernel(const float4* __restrict__ ps4,
                                                      const unsigned int* __restrict__ p14arr,
                                                      u64* __restrict__ cand,
                                                      unsigned int* __restrict__ cnt) {
    __shared__ u64 sl[2048];
    __shared__ int lcnt;
    __shared__ unsigned int lbase;
    const int t = threadIdx.x;
    if (t == 0) lcnt = 0;
    __syncthreads();
    const int b = blockIdx.y;
    const unsigned int p14 = p14arr[b];
    const float4* p = ps4 + (size_t)b * N4;
    for (int k = 0; k < 2; ++k) {
        int i4 = blockIdx.x * 512 + k * 256 + t;
        if (i4 < N4) {
            float4 v = p[i4];
            int n = i4 << 2;
            unsigned int u;
            u = ordkey(v.x);
            if ((u >> HSHIFT) >= p14) { int pos = atomicAdd(&lcnt, 1);
                sl[pos] = ((u64)u << 32) | (unsigned int)(~(unsigned int)(n)); }
            u = ordkey(v.y);
            if ((u >> HSHIFT) >= p14) { int pos = atomicAdd(&lcnt, 1);
                sl[pos] = ((u64)u << 32) | (unsigned int)(~(unsigned int)(n + 1)); }
            u = ordkey(v.z);
            if ((u >> HSHIFT) >= p14) { int pos = atomicAdd(&lcnt, 1);
                sl[pos] = ((u64)u << 32) | (unsigned int)(~(unsigned int)(n + 2)); }
            u = ordkey(v.w);
            if ((u >> HSHIFT) >= p14) { int pos = atomicAdd(&lcnt, 1);
                sl[pos] = ((u64)u << 32) | (unsigned int)(~(unsigned int)(n + 3)); }
        }
    }
    __syncthreads();
    if (t == 0 && lcnt > 0) lbase = atomicAdd(&cnt[b * CNT_STRIDE], (unsigned)lcnt);
    __syncthreads();
    for (int i = t; i < lcnt; i += 256) {
        unsigned int pos = lbase + (unsigned)i;
        if (pos < CAND_CAP) cand[(size_t)b * CAND_CAP + pos] = sl[i];
    }
}

// ---- per-batch: radix-select + rank top-500, class-partitioned NMS ----
__global__ __launch_bounds__(1024) void final_kernel(const float* __restrict__ pboxes,
                                                     const int* __restrict__ plabels,
                                                     const u64* __restrict__ cand,
                                                     const unsigned int* __restrict__ cnt,
                                                     float* __restrict__ out) {
    __shared__ u64 kbuf[CAND_CAP];      // keys, later IoU mask rows (500*8)
    __shared__ u64 sel[1024];           // selected keys, then sorted top-500
    __shared__ float sboxes[KK][4];
    __shared__ float sshift[KK][4];
    __shared__ float sscore[KK];
    __shared__ int slabel[KK];
    __shared__ unsigned int h[256];
    __shared__ int clist[KK];
    __shared__ int ccnt[21], coff[22], cfill[21];
    __shared__ u64 validw[8];
    __shared__ int kept[KEEPN];
    __shared__ float wred[16];
    __shared__ u64 s_prefix;
    __shared__ unsigned int s_bin, s_region, s_cntgt;
    __shared__ int s_sc, s_nk;
    __shared__ float s_maxc;

    const int b = blockIdx.x;
    const int tid = threadIdx.x;
    const int lane = tid & 63;

    int m = (int)cnt[b * CNT_STRIDE];
    if (m > CAND_CAP) m = CAND_CAP;

    for (int i = tid; i < m; i += 1024)
        kbuf[i] = cand[(size_t)b * CAND_CAP + i];
    __syncthreads();

    // ---- radix-select: narrow to <=1024 keys >= thr ----
    u64 thr; int seln;
    if (m <= 1024) {
        thr = 0ULL; seln = m;
    } else {
        if (tid == 0) { s_prefix = 0ULL; s_cntgt = 0u; }
        __syncthreads();
        int shift = 56;
        for (; shift >= 0; shift -= 8) {
            if (tid < 256) h[tid] = 0u;
            __syncthreads();
            u64 pref = s_prefix;
            unsigned int cg = s_cntgt;
            for (int i = tid; i < m; i += 1024) {
                u64 k = kbuf[i];
                bool match = (shift == 56) || ((k >> (shift + 8)) == pref);
                if (match) atomicAdd(&h[(unsigned int)((k >> shift) & 0xFF)], 1u);
            }
            __syncthreads();
            for (int d = 1; d < 256; d <<= 1) {
                unsigned int add = (tid < 256 && tid + d < 256) ? h[tid + d] : 0u;
                __syncthreads();
                if (tid < 256) h[tid] += add;
                __syncthreads();
            }
            unsigned int target = (unsigned)KK - cg;
            if (tid < 256) {
                unsigned int st = h[tid];
                unsigned int stn = (tid < 255) ? h[tid + 1] : 0u;
                if (st >= target && stn < target) s_bin = (unsigned)tid;
            }
            __syncthreads();
            if (tid == 0) {
                unsigned int bin = s_bin;
                unsigned int sfx1 = (bin < 255) ? h[bin + 1] : 0u;
                s_region = h[bin] - sfx1;
                s_cntgt = cg + sfx1;
                s_prefix = (shift == 56) ? (u64)bin : ((pref << 8) | (u64)bin);
            }
            __syncthreads();
            if (s_cntgt + s_region <= 1024u) break;
        }
        thr = s_prefix << shift;
        seln = (int)(s_cntgt + s_region);
    }

    // ---- selection: gather keys >= thr into sel[] (wave-aggregated atomic) ----
    if (tid == 0) s_sc = 0;
    __syncthreads();
    for (int r = 0; r < 4; ++r) {
        int i = tid + r * 1024;
        u64 k = (i < m) ? kbuf[i] : 0ULL;
        bool p = (i < m) && (k >= thr);
        u64 mb = __ballot(p);
        int pre = __popcll(mb & ((1ULL << lane) - 1ULL));
        int tot = __popcll(mb);
        int base = 0;
        if (lane == 0 && tot > 0) base = atomicAdd(&s_sc, tot);
        base = __shfl(base, 0);
        if (p) sel[base + pre] = k;
    }
    __syncthreads();

    // ---- brute-force rank (keys unique), scatter sorted top-500 ----
    u64 myk = 0ULL; int myr = 0x7FFFFFFF;
    if (tid < seln) {
        myk = sel[tid];
        int r = 0;
        for (int j = 0; j < seln; ++j) r += (sel[j] > myk) ? 1 : 0;
        myr = r;
    }
    __syncthreads();
    if (tid < seln && myr < KK) sel[myr] = myk;
    __syncthreads();

    // ---- extract, gather boxes/labels ----
    float sc = -1.0f;
    if (tid < KK) {
        u64 key = sel[tid];
        unsigned int lo = (unsigned int)key;
        unsigned int hi = (unsigned int)(key >> 32);
        int idx = (int)(~lo);
        unsigned int bits = (hi & 0x80000000u) ? (hi & 0x7FFFFFFFu) : ~hi;
        sc = __uint_as_float(bits);
        sscore[tid] = sc;
        const float4 bx = *(const float4*)(pboxes + (((size_t)b * NN + (size_t)idx) << 2));
        sboxes[tid][0] = bx.x; sboxes[tid][1] = bx.y;
        sboxes[tid][2] = bx.z; sboxes[tid][3] = bx.w;
        slabel[tid] = plabels[(size_t)b * NN + idx];
    }
    __syncthreads();

    // ---- valid mask + max_coord ----
    bool v = (tid < KK) && (sc > CONF);
    u64 bm = __ballot(v);
    if (lane == 0 && (tid >> 6) < 8) validw[tid >> 6] = bm;
    float lm = 0.0f;
    if (v) lm = fmaxf(fmaxf(sboxes[tid][0], sboxes[tid][1]),
                      fmaxf(sboxes[tid][2], sboxes[tid][3]));
    for (int off = 32; off > 0; off >>= 1) lm = fmaxf(lm, __shfl_down(lm, off));
    if (lane == 0) wred[tid >> 6] = lm;
    __syncthreads();
    if (tid < 64) {
        float x = (tid < 16) ? wred[tid] : 0.0f;
        for (int off = 8; off > 0; off >>= 1) x = fmaxf(x, __shfl_down(x, off));
        if (tid == 0) s_maxc = x;
    }
    __syncthreads();

    // ---- shifted boxes (exact reference arithmetic) ----
    if (tid < KK) {
        float off = (float)slabel[tid] * (s_maxc + 1.0f);
        sshift[tid][0] = sboxes[tid][0] + off;
        sshift[tid][1] = sboxes[tid][1] + off;
        sshift[tid][2] = sboxes[tid][2] + off;
        sshift[tid][3] = sboxes[tid][3] + off;
    }
    // ---- class member lists (cross-label IoU is exactly 0 after offsets) ----
    if (tid < 21) { ccnt[tid] = 0; cfill[tid] = 0; }
    __syncthreads();
    if (tid < KK) atomicAdd(&ccnt[slabel[tid]], 1);
    __syncthreads();
    if (tid == 0) {
        int acc = 0;
        for (int c = 0; c < 21; ++c) { coff[c] = acc; acc += ccnt[c]; }
        coff[21] = acc;
    }
    __syncthreads();
    if (tid < KK) {
        int c = slabel[tid];
        int pos = atomicAdd(&cfill[c], 1);
        clist[coff[c] + pos] = tid;
    }
    // zero mask rows (kbuf reuse)
    for (int i = tid; i < KK * 8; i += 1024) kbuf[i] = 0ULL;
    __syncthreads();

    // ---- IoU > thr bitmask rows: thread i vs same-class members only ----
    if (tid < KK) {
        int c = slabel[tid];
        int n = ccnt[c], base = coff[c];
        float a0 = sshift[tid][0], a1 = sshift[tid][1],
              a2 = sshift[tid][2], a3 = sshift[tid][3];
        float areaA = (a2 - a0) * (a3 - a1);
        for (int q = 0; q < n; ++q) {
            int j = clist[base + q];
            float b0 = sshift[j][0], b1f = sshift[j][1],
                  b2f = sshift[j][2], b3f = sshift[j][3];
            float lt0 = fmaxf(a0, b0), lt1 = fmaxf(a1, b1f);
            float rb0 = fminf(a2, b2f), rb1 = fminf(a3, b3f);
            float ww = fmaxf(rb0 - lt0, 0.0f), hh = fmaxf(rb1 - lt1, 0.0f);
            float inter = ww * hh;
            float areaB = (b2f - b0) * (b3f - b1f);
            float iou = inter / (areaA + areaB - inter);
            if (iou > NMSTHR) kbuf[tid * 8 + (j >> 6)] |= (1ULL << (j & 63));
        }
    }
    __syncthreads();

    // ---- greedy scan on wave 0; early-exit at KEEPN ----
    if (tid < 64) {
        u64 remv = 0ULL;
        u64 vw_reg = (lane < 8) ? validw[lane] : 0ULL;
        int nk = 0;
        for (int i = 0; i < KK && nk < KEEPN; ++i) {
            int w = i >> 6, bpos = i & 63;
            u64 rw = __shfl(remv, w);
            u64 vv = __shfl(vw_reg, w);
            bool alive = (((vv >> bpos) & 1ULL) != 0ULL) && (((rw >> bpos) & 1ULL) == 0ULL);
            if (alive) {
                if (lane == 0) kept[nk] = i;
                u64 roww = (lane < 8) ? kbuf[i * 8 + lane] : 0ULL;
                remv |= roww;
                nk++;
            }
        }
        if (lane == 0) s_nk = nk;
    }
    __syncthreads();

    // ---- outputs (all float32, concatenated in reference return order) ----
    if (tid < KEEPN) {
        const int O_BOX = BB * KEEPN;
        const int O_LAB = BB * KEEPN * 5;
        const int O_SCO = BB * KEEPN * 6;
        const int O_VAL = BB * KEEPN * 7;
        bool q = tid < s_nk;
        int i = q ? kept[tid] : 0;
        int g = b * KEEPN + tid;
        out[g]                 = q ? (float)b : -1.0f;
        out[O_BOX + g * 4 + 0] = q ? sboxes[i][0] : 0.0f;
        out[O_BOX + g * 4 + 1] = q ? sboxes[i][1] : 0.0f;
        out[O_BOX + g * 4 + 2] = q ? sboxes[i][2] : 0.0f;
        out[O_BOX + g * 4 + 3] = q ? sboxes[i][3] : 0.0f;
        out[O_LAB + g]         = q ? (float)slabel[i] : -1.0f;
        out[O_SCO + g]         = q ? sscore[i] : 0.0f;
        out[O_VAL + g]         = q ? 1.0f : 0.0f;
    }
}

extern "C" void kernel_launch(void* const* d_in, const int* in_sizes, int n_in,
                              void* d_out, int out_size, void* d_ws, size_t ws_size,
                              hipStream_t stream) {
    const float* pscores = (const float*)d_in[0];
    const float* pboxes  = (const float*)d_in[1];
    const int*   plabels = (const int*)d_in[2];
    float* out = (float*)d_out;

    uint8_t* ws = (uint8_t*)d_ws;
    unsigned int* hist = (unsigned int*)(ws + 0);
    unsigned int* cnt  = (unsigned int*)(ws + 2097152);
    unsigned int* p14  = (unsigned int*)(ws + 2099200);
    u64*          cand = (u64*)(ws + 2099328);

    hipMemsetAsync(hist, 0, 32 * HBINS * 4, stream);

    hist_kernel<<<dim3(8, BB), 512, 0, stream>>>((const float4*)pscores, hist);
    scan_kernel<<<BB, 1024, 0, stream>>>(hist, p14, cnt);
    compact_kernel<<<dim3((N4 + 511) / 512, BB), 256, 0, stream>>>(
        (const float4*)pscores, p14, cand, cnt);
    final_kernel<<<BB, 1024, 0, stream>>>(pboxes, plabels, cand, cnt, out);
}